// Round 2
// baseline (832.551 us; speedup 1.0000x reference)
//
#include <hip/hip_runtime.h>

#define S_DIM 256
#define R_DIM 384
#define C_DIM 256
#define H_DIM 8
#define AC_DIM 32
#define HC_DIM 256
#define M_DIM (S_DIM * R_DIM)  // 98304 rows, m = r*S + s

typedef __attribute__((ext_vector_type(8))) short short8;
typedef __attribute__((ext_vector_type(4))) float floatx4;

__device__ __forceinline__ unsigned short f2bf(float f) {
  unsigned u = __float_as_uint(f);
  u += 0x7FFFu + ((u >> 16) & 1u);  // round-to-nearest-even
  return (unsigned short)(u >> 16);
}
__device__ __forceinline__ float bf2f(unsigned short s) {
  return __uint_as_float(((unsigned)s) << 16);
}
__device__ __forceinline__ unsigned packbf2(float a, float b) {
  return (unsigned)f2bf(a) | ((unsigned)f2bf(b) << 16);
}

// async global->LDS, 16B per lane; LDS dest = wave-uniform base + lane*16
#define GLD_LDS16(gp, lp)                                                      \
  __builtin_amdgcn_global_load_lds(                                            \
      (const __attribute__((address_space(1))) unsigned int*)(gp),             \
      (__attribute__((address_space(3))) unsigned int*)(lp), 16, 0, 0)

// ---------------------------------------------------------------------------
// Kernel A: weight pre-pass. Wt[n][k] bf16, n in [0,1280):
//   n<1024: {wq,wk,wv,wg}[k][n&255]; n>=1024: wo[k][n&255].
// ---------------------------------------------------------------------------
__global__ __launch_bounds__(256) void wcat_kernel(
    const float* __restrict__ wq, const float* __restrict__ wk,
    const float* __restrict__ wv, const float* __restrict__ wg,
    const float* __restrict__ wo, unsigned short* __restrict__ wt) {
  __shared__ float tile[64][65];
  const int n0 = blockIdx.x * 64;  // 0..1216
  const int k0 = blockIdx.y * 64;
  const int wi = n0 >> 8;
  const float* src = (wi == 0) ? wq : (wi == 1) ? wk : (wi == 2) ? wv
                   : (wi == 3) ? wg : wo;
  const int col0 = n0 & 255;
  const int tx = threadIdx.x & 63;
  const int ty = threadIdx.x >> 6;
#pragma unroll
  for (int i = 0; i < 16; ++i) {
    int kl = ty + i * 4;
    tile[kl][tx] = src[(size_t)(k0 + kl) * 256 + col0 + tx];
  }
  __syncthreads();
#pragma unroll
  for (int i = 0; i < 16; ++i) {
    int nl = ty + i * 4;
    wt[(size_t)(n0 + nl) * 256 + k0 + tx] = f2bf(tile[tx][nl]);
  }
}

// ---------------------------------------------------------------------------
// Kernel B: fused LayerNorm -> bf16 x_ln in m-order (m = r*S + s).
// ---------------------------------------------------------------------------
__global__ __launch_bounds__(256) void ln_kernel(
    const float* __restrict__ msa, const float* __restrict__ ln_g,
    const float* __restrict__ ln_b, unsigned short* __restrict__ xln) {
  const int p = blockIdx.x * 4 + (threadIdx.x >> 6);
  const int lane = threadIdx.x & 63;
  const float4 v = ((const float4*)(msa + (size_t)p * C_DIM))[lane];
  float s = v.x + v.y + v.z + v.w;
  float ss = v.x * v.x + v.y * v.y + v.z * v.z + v.w * v.w;
#pragma unroll
  for (int o = 1; o < 64; o <<= 1) {
    s += __shfl_xor(s, o);
    ss += __shfl_xor(ss, o);
  }
  const float mu = s * (1.0f / C_DIM);
  const float rstd = rsqrtf(ss * (1.0f / C_DIM) - mu * mu + 1e-5f);
  const float4 g = ((const float4*)ln_g)[lane];
  const float4 b = ((const float4*)ln_b)[lane];
  const int sq = p / R_DIM;          // s
  const int r = p - sq * R_DIM;      // r
  const size_t m = (size_t)r * S_DIM + sq;
  ushort4 o;
  o.x = f2bf((v.x - mu) * rstd * g.x + b.x);
  o.y = f2bf((v.y - mu) * rstd * g.y + b.y);
  o.z = f2bf((v.z - mu) * rstd * g.z + b.z);
  o.w = f2bf((v.w - mu) * rstd * g.w + b.w);
  *(ushort4*)(xln + m * C_DIM + lane * 4) = o;
}

// ---------------------------------------------------------------------------
// Kernel C: projection GEMM v3 — persistent-B software pipeline.
// Each block: one n-tile (128 cols), G=8 consecutive m-tiles (1024 rows).
// B (128x256, 64KB) staged once -> 32 short8 frags in REGISTERS.
// A panels double-buffered in LDS (2 x 64KB = 128 KiB); panel mt+1's 16
// global_load_lds are in flight while panel mt computes. One barrier per
// m-tile; its vmcnt drain hits ~1000-cy-old loads (cheap).
// Grid 768 = 3 exact rounds of 256 CUs, 1 block/CU (LDS-limited by design).
// XCD digit-swizzle: 8 n-blocks of one m-group co-resident on one XCD.
// ---------------------------------------------------------------------------
__global__ __launch_bounds__(256, 1) void proj_kernel(
    const unsigned short* __restrict__ xln, const unsigned short* __restrict__ wt,
    const float* __restrict__ bg, unsigned short* __restrict__ q_ws,
    unsigned short* __restrict__ k_ws, unsigned short* __restrict__ v_ws,
    unsigned short* __restrict__ g_ws) {
  __shared__ __align__(16) unsigned short As[2][8 * 8 * 512];  // 2 x 64 KB

  // bid = (g>>3)*64 + x*8 + (g&7): bijective over 768; XCD = bid%8 = g%8,
  // so the 8 n-blocks (x=0..7) of m-group g share an XCD, bids within 64.
  const int bid = blockIdx.x;
  const int g = ((bid >> 6) << 3) + (bid & 7);  // m-group 0..95
  const int x = (bid >> 3) & 7;                 // n-tile 0..7
  const int n0 = x << 7;
  const int m0 = g << 10;  // g * 1024

  const int tid = threadIdx.x;
  const int wave = tid >> 6, lane = tid & 63;
  const int qd = lane >> 4, lm = lane & 15;
  const int wm = (wave & 1) * 64, wn = (wave >> 1) * 64;
  const int ga0 = wave * 2, ga1 = wave * 2 + 1;

  // ---- stage B (into As[1], temporarily) and A panel 0 (into As[0]) ----
  const unsigned short* bgp0 = wt + (size_t)(n0 + ga0 * 16 + lm) * 256 + qd * 8;
  const unsigned short* bgp1 = wt + (size_t)(n0 + ga1 * 16 + lm) * 256 + qd * 8;
#pragma unroll
  for (int c = 0; c < 8; ++c) {
    GLD_LDS16(bgp0 + c * 32, &As[1][(c * 8 + ga0) * 512]);
    GLD_LDS16(bgp1 + c * 32, &As[1][(c * 8 + ga1) * 512]);
  }
  const unsigned short* agp0 = xln + (size_t)(m0 + ga0 * 16 + lm) * 256 + qd * 8;
  const unsigned short* agp1 = xln + (size_t)(m0 + ga1 * 16 + lm) * 256 + qd * 8;
#pragma unroll
  for (int c = 0; c < 8; ++c) {
    GLD_LDS16(agp0 + c * 32, &As[0][(c * 8 + ga0) * 512]);
    GLD_LDS16(agp1 + c * 32, &As[0][(c * 8 + ga1) * 512]);
  }
  __syncthreads();  // B + panel0 staged

  // ---- B frags -> registers (persistent for the whole block) ----
  short8 breg[8][4];
#pragma unroll
  for (int c = 0; c < 8; ++c)
#pragma unroll
    for (int t = 0; t < 4; ++t)
      breg[c][t] = *(const short8*)((const char*)&As[1][0] +
                                    (size_t)(c * 8 + wn / 16 + t) * 1024 + lane * 16);
  __syncthreads();  // all waves done reading As[1]; it becomes A buffer 1

  const int wi = n0 >> 8;
  const int colbase = (n0 & 255) + wn;

  for (int mt = 0; mt < 8; ++mt) {
    __syncthreads();  // panel mt resident in As[mt&1]; As[(mt+1)&1] free

    if (mt < 7) {  // issue panel mt+1 loads; they fly under this tile's MFMAs
      const unsigned short* pa0 = agp0 + (size_t)(mt + 1) * 128 * 256;
      const unsigned short* pa1 = agp1 + (size_t)(mt + 1) * 128 * 256;
      unsigned short* dst = &As[(mt + 1) & 1][0];
#pragma unroll
      for (int c = 0; c < 8; ++c) {
        GLD_LDS16(pa0 + c * 32, dst + (c * 8 + ga0) * 512);
        GLD_LDS16(pa1 + c * 32, dst + (c * 8 + ga1) * 512);
      }
    }

    const char* Ab = (const char*)&As[mt & 1][0];
    floatx4 acc[4][4];
#pragma unroll
    for (int i = 0; i < 4; ++i)
#pragma unroll
      for (int j = 0; j < 4; ++j) acc[i][j] = (floatx4){0.f, 0.f, 0.f, 0.f};

#pragma unroll
    for (int c = 0; c < 8; ++c) {
      short8 af[4];
#pragma unroll
      for (int t = 0; t < 4; ++t)
        af[t] = *(const short8*)(Ab + (size_t)(c * 8 + wm / 16 + t) * 1024 + lane * 16);
#pragma unroll
      for (int tm = 0; tm < 4; ++tm)
#pragma unroll
        for (int tn = 0; tn < 4; ++tn)
          acc[tm][tn] = __builtin_amdgcn_mfma_f32_16x16x32_bf16(
              af[tm], breg[c][tn], acc[tm][tn], 0, 0, 0);
    }

    const int mbase = m0 + mt * 128 + wm;
#pragma unroll
    for (int tm = 0; tm < 4; ++tm)
#pragma unroll
      for (int tn = 0; tn < 4; ++tn)
#pragma unroll
        for (int rg = 0; rg < 4; ++rg) {
          const int m = mbase + tm * 16 + qd * 4 + rg;
          const int col = colbase + tn * 16 + lm;
          const size_t off = (size_t)m * 256 + col;
          float val = acc[tm][tn][rg];
          if (wi == 0) {
            q_ws[off] = f2bf(val * 0.17677669529663689f);  // 1/sqrt(32)
          } else if (wi == 1) {
            k_ws[off] = f2bf(val);
          } else if (wi == 2) {
            v_ws[off] = f2bf(val);
          } else {
            g_ws[off] = f2bf(1.0f / (1.0f + __expf(-(val + bg[col]))));
          }
        }
  }
}

// ---------------------------------------------------------------------------
// Kernel D: flash-style MFMA attention per (r, h) — unchanged.
// ---------------------------------------------------------------------------
#define PSTRIDE 40
#define VSTRIDE 264

__global__ __launch_bounds__(256) void attn_kernel(
    const unsigned short* __restrict__ q_ws, const unsigned short* __restrict__ k_ws,
    const unsigned short* __restrict__ v_ws, const unsigned short* __restrict__ g_ws,
    const float* __restrict__ mask, unsigned short* __restrict__ ctx_ws) {
  __shared__ __align__(16) unsigned short V_lds[32 * VSTRIDE];
  __shared__ __align__(16) unsigned short P_lds[4 * 16 * PSTRIDE];
  __shared__ float Bias[S_DIM];

  const int r = blockIdx.x;
  const int h = blockIdx.y;
  const int tid = threadIdx.x;
  const int wave = tid >> 6, lane = tid & 63;
  const int qd = lane >> 4, lm = lane & 15;
  const int qw = wave * 64;

  const size_t rS = (size_t)r * S_DIM;
  const int hb = h * AC_DIM;

  {
    const int s = tid;
    const unsigned short* vp = v_ws + (rS + s) * HC_DIM + hb;
    const int pos = (s & ~31) + ((s & 15) * 2) + ((s >> 4) & 1);
    uint4 u0 = *(const uint4*)(vp);
    uint4 u1 = *(const uint4*)(vp + 8);
    uint4 u2 = *(const uint4*)(vp + 16);
    uint4 u3 = *(const uint4*)(vp + 24);
    const unsigned w[16] = {u0.x, u0.y, u0.z, u0.w, u1.x, u1.y, u1.z, u1.w,
                            u2.x, u2.y, u2.z, u2.w, u3.x, u3.y, u3.z, u3.w};
#pragma unroll
    for (int d2 = 0; d2 < 16; ++d2) {
      V_lds[(d2 * 2 + 0) * VSTRIDE + pos] = (unsigned short)(w[d2] & 0xFFFF);
      V_lds[(d2 * 2 + 1) * VSTRIDE + pos] = (unsigned short)(w[d2] >> 16);
    }
    Bias[s] = 1e9f * (mask[(size_t)s * R_DIM + r] - 1.0f);
  }

  short8 qf[4];
#pragma unroll
  for (int qi = 0; qi < 4; ++qi)
    qf[qi] = *(const short8*)(q_ws + (rS + qw + qi * 16 + lm) * HC_DIM + hb + qd * 8);

  float m_st[4][4], l_st[4][4];
  floatx4 oacc[4][2];
#pragma unroll
  for (int qi = 0; qi < 4; ++qi) {
#pragma unroll
    for (int rg = 0; rg < 4; ++rg) {
      m_st[qi][rg] = -1e30f;
      l_st[qi][rg] = 0.0f;
    }
    oacc[qi][0] = (floatx4){0.f, 0.f, 0.f, 0.f};
    oacc[qi][1] = (floatx4){0.f, 0.f, 0.f, 0.f};
  }

  __syncthreads();

  unsigned short* Pw = &P_lds[wave * 16 * PSTRIDE];
  const floatx4 zero4 = (floatx4){0.f, 0.f, 0.f, 0.f};

  for (int ch = 0; ch < 8; ++ch) {
    const int kb = ch * 32;
    const float b0 = Bias[kb + lm];
    const float b1 = Bias[kb + 16 + lm];
    short8 kf0 = *(const short8*)(k_ws + (rS + kb + lm) * HC_DIM + hb + qd * 8);
    short8 kf1 = *(const short8*)(k_ws + (rS + kb + 16 + lm) * HC_DIM + hb + qd * 8);
    short8 vf0 = *(const short8*)&V_lds[lm * VSTRIDE + kb + qd * 8];
    short8 vf1 = *(const short8*)&V_lds[(16 + lm) * VSTRIDE + kb + qd * 8];

#pragma unroll
    for (int qi = 0; qi < 4; ++qi) {
      floatx4 s0 = __builtin_amdgcn_mfma_f32_16x16x32_bf16(qf[qi], kf0, zero4, 0, 0, 0);
      floatx4 s1 = __builtin_amdgcn_mfma_f32_16x16x32_bf16(qf[qi], kf1, zero4, 0, 0, 0);
      unsigned pw[4];
#pragma unroll
      for (int rg = 0; rg < 4; ++rg) {
        float a0 = s0[rg] + b0;
        float a1 = s1[rg] + b1;
        float t = fmaxf(a0, a1);
        t = fmaxf(t, __shfl_xor(t, 1));
        t = fmaxf(t, __shfl_xor(t, 2));
        t = fmaxf(t, __shfl_xor(t, 4));
        t = fmaxf(t, __shfl_xor(t, 8));
        float mold = m_st[qi][rg];
        float mnew = fmaxf(mold, t);
        float alpha = __expf(mold - mnew);
        float p0 = __expf(a0 - mnew);
        float p1 = __expf(a1 - mnew);
        float rs = p0 + p1;
        rs += __shfl_xor(rs, 1);
        rs += __shfl_xor(rs, 2);
        rs += __shfl_xor(rs, 4);
        rs += __shfl_xor(rs, 8);
        l_st[qi][rg] = l_st[qi][rg] * alpha + rs;
        m_st[qi][rg] = mnew;
        oacc[qi][0][rg] *= alpha;
        oacc[qi][1][rg] *= alpha;
        pw[rg] = packbf2(p0, p1);
      }
      unsigned* pbase = (unsigned*)Pw;
#pragma unroll
      for (int rg = 0; rg < 4; ++rg)
        pbase[((qd * 4 + rg) * PSTRIDE) / 2 + lm] = pw[rg];
      short8 pa = *(const short8*)&Pw[lm * PSTRIDE + qd * 8];
      oacc[qi][0] = __builtin_amdgcn_mfma_f32_16x16x32_bf16(pa, vf0, oacc[qi][0], 0, 0, 0);
      oacc[qi][1] = __builtin_amdgcn_mfma_f32_16x16x32_bf16(pa, vf1, oacc[qi][1], 0, 0, 0);
    }
  }

#pragma unroll
  for (int qi = 0; qi < 4; ++qi) {
#pragma unroll
    for (int rg = 0; rg < 4; ++rg) {
      const float inv = 1.0f / l_st[qi][rg];
      const int row = qw + qi * 16 + qd * 4 + rg;
      const size_t base = (rS + row) * HC_DIM + hb;
      float o0 = oacc[qi][0][rg] * inv * bf2f(g_ws[base + lm]);
      float o1 = oacc[qi][1][rg] * inv * bf2f(g_ws[base + 16 + lm]);
      ctx_ws[base + lm] = f2bf(o0);
      ctx_ws[base + 16 + lm] = f2bf(o1);
    }
  }
}

// ---------------------------------------------------------------------------
// Kernel E: out = ctx @ wo + bo -> fp32 [S,R,C]. Same v3 pipeline as proj.
// G=6 m-tiles/block, 2 n-tiles -> grid 256 = exactly 1 block/CU, 1 round.
// ---------------------------------------------------------------------------
__global__ __launch_bounds__(256, 1) void out_kernel(
    const unsigned short* __restrict__ ctx, const unsigned short* __restrict__ wot,
    const float* __restrict__ bo, float* __restrict__ out) {
  __shared__ __align__(16) unsigned short As[2][8 * 8 * 512];  // 2 x 64 KB

  // bid = (g>>3)*16 + x*8 + (g&7): bijective over 256; XCD = g%8.
  const int bid = blockIdx.x;
  const int g = ((bid >> 4) << 3) + (bid & 7);  // m-group 0..127
  const int x = (bid >> 3) & 1;                 // n-tile 0..1
  const int n0 = x << 7;
  const int m0 = g * 768;  // 6 m-tiles of 128

  const int tid = threadIdx.x;
  const int wave = tid >> 6, lane = tid & 63;
  const int qd = lane >> 4, lm = lane & 15;
  const int wm = (wave & 1) * 64, wn = (wave >> 1) * 64;
  const int ga0 = wave * 2, ga1 = wave * 2 + 1;

  const unsigned short* bgp0 = wot + (size_t)(n0 + ga0 * 16 + lm) * 256 + qd * 8;
  const unsigned short* bgp1 = wot + (size_t)(n0 + ga1 * 16 + lm) * 256 + qd * 8;
#pragma unroll
  for (int c = 0; c < 8; ++c) {
    GLD_LDS16(bgp0 + c * 32, &As[1][(c * 8 + ga0) * 512]);
    GLD_LDS16(bgp1 + c * 32, &As[1][(c * 8 + ga1) * 512]);
  }
  const unsigned short* agp0 = ctx + (size_t)(m0 + ga0 * 16 + lm) * 256 + qd * 8;
  const unsigned short* agp1 = ctx + (size_t)(m0 + ga1 * 16 + lm) * 256 + qd * 8;
#pragma unroll
  for (int c = 0; c < 8; ++c) {
    GLD_LDS16(agp0 + c * 32, &As[0][(c * 8 + ga0) * 512]);
    GLD_LDS16(agp1 + c * 32, &As[0][(c * 8 + ga1) * 512]);
  }
  __syncthreads();

  short8 breg[8][4];
#pragma unroll
  for (int c = 0; c < 8; ++c)
#pragma unroll
    for (int t = 0; t < 4; ++t)
      breg[c][t] = *(const short8*)((const char*)&As[1][0] +
                                    (size_t)(c * 8 + wn / 16 + t) * 1024 + lane * 16);
  __syncthreads();

  for (int mt = 0; mt < 6; ++mt) {
    __syncthreads();

    if (mt < 5) {
      const unsigned short* pa0 = agp0 + (size_t)(mt + 1) * 128 * 256;
      const unsigned short* pa1 = agp1 + (size_t)(mt + 1) * 128 * 256;
      unsigned short* dst = &As[(mt + 1) & 1][0];
#pragma unroll
      for (int c = 0; c < 8; ++c) {
        GLD_LDS16(pa0 + c * 32, dst + (c * 8 + ga0) * 512);
        GLD_LDS16(pa1 + c * 32, dst + (c * 8 + ga1) * 512);
      }
    }

    const char* Ab = (const char*)&As[mt & 1][0];
    floatx4 acc[4][4];
#pragma unroll
    for (int i = 0; i < 4; ++i)
#pragma unroll
      for (int j = 0; j < 4; ++j) acc[i][j] = (floatx4){0.f, 0.f, 0.f, 0.f};

#pragma unroll
    for (int c = 0; c < 8; ++c) {
      short8 af[4];
#pragma unroll
      for (int t = 0; t < 4; ++t)
        af[t] = *(const short8*)(Ab + (size_t)(c * 8 + wm / 16 + t) * 1024 + lane * 16);
#pragma unroll
      for (int tm = 0; tm < 4; ++tm)
#pragma unroll
        for (int tn = 0; tn < 4; ++tn)
          acc[tm][tn] = __builtin_amdgcn_mfma_f32_16x16x32_bf16(
              af[tm], breg[c][tn], acc[tm][tn], 0, 0, 0);
    }

    const int mbase = m0 + mt * 128 + wm;
#pragma unroll
    for (int tm = 0; tm < 4; ++tm)
#pragma unroll
      for (int tn = 0; tn < 4; ++tn)
#pragma unroll
        for (int rg = 0; rg < 4; ++rg) {
          const int m = mbase + tm * 16 + qd * 4 + rg;
          const int n = n0 + wn + tn * 16 + lm;
          const int rr = m >> 8;   // r
          const int sc = m & 255;  // s
          out[((size_t)sc * R_DIM + rr) * C_DIM + n] = acc[tm][tn][rg] + bo[n];
        }
  }
}

// ---------------------------------------------------------------------------
extern "C" void kernel_launch(void* const* d_in, const int* in_sizes, int n_in,
                              void* d_out, int out_size, void* d_ws, size_t ws_size,
                              hipStream_t stream) {
  const float* msa = (const float*)d_in[0];
  const float* mask = (const float*)d_in[1];
  const float* ln_g = (const float*)d_in[2];
  const float* ln_b = (const float*)d_in[3];
  const float* wq = (const float*)d_in[4];
  const float* wk = (const float*)d_in[5];
  const float* wv = (const float*)d_in[6];
  const float* wg = (const float*)d_in[7];
  const float* bg = (const float*)d_in[8];
  const float* wo = (const float*)d_in[9];
  const float* bo = (const float*)d_in[10];
  float* out = (float*)d_out;

  // workspace carve (~252.3 MB): Wt | x_ln (aliased as ctx) | q | k | v | g
  unsigned short* wt = (unsigned short*)d_ws;
  unsigned short* xln = wt + (size_t)1280 * 256;
  unsigned short* q_ws = xln + (size_t)M_DIM * 256;
  unsigned short* k_ws = q_ws + (size_t)M_DIM * 256;
  unsigned short* v_ws = k_ws + (size_t)M_DIM * 256;
  unsigned short* g_ws = v_ws + (size_t)M_DIM * 256;
  unsigned short* ctx_ws = xln;  // alias: x_ln dead after proj
  unsigned short* wot = wt + (size_t)1024 * 256;

  hipLaunchKernelGGL(wcat_kernel, dim3(20, 4), dim3(256), 0, stream,
                     wq, wk, wv, wg, wo, wt);
  hipLaunchKernelGGL(ln_kernel, dim3(M_DIM / 4), dim3(256), 0, stream,
                     msa, ln_g, ln_b, xln);
  hipLaunchKernelGGL(proj_kernel, dim3(768), dim3(256), 0, stream,
                     xln, wt, bg, q_ws, k_ws, v_ws, g_ws);
  hipLaunchKernelGGL(attn_kernel, dim3(R_DIM, H_DIM), dim3(256), 0, stream,
                     q_ws, k_ws, v_ws, g_ws, mask, ctx_ws);
  hipLaunchKernelGGL(out_kernel, dim3(2 * (M_DIM / 128) / 6), dim3(256), 0, stream,
                     ctx_ws, wot, bo, out);
}

// Round 4
// 551.804 us; speedup vs baseline: 1.5088x; 1.5088x over previous
//
#include <hip/hip_runtime.h>

#define S_DIM 256
#define R_DIM 384
#define C_DIM 256
#define H_DIM 8
#define AC_DIM 32
#define HC_DIM 256
#define M_DIM (S_DIM * R_DIM)  // 98304 rows, m = r*S + s

typedef __attribute__((ext_vector_type(8))) short short8;
typedef __attribute__((ext_vector_type(4))) float floatx4;

__device__ __forceinline__ unsigned short f2bf(float f) {
  unsigned u = __float_as_uint(f);
  u += 0x7FFFu + ((u >> 16) & 1u);  // round-to-nearest-even
  return (unsigned short)(u >> 16);
}
__device__ __forceinline__ float bf2f(unsigned short s) {
  return __uint_as_float(((unsigned)s) << 16);
}
__device__ __forceinline__ unsigned packbf2(float a, float b) {
  return (unsigned)f2bf(a) | ((unsigned)f2bf(b) << 16);
}

// async global->LDS, 16B per lane; LDS dest = wave-uniform base + lane*16
#define GLD_LDS16(gp, lp)                                                      \
  __builtin_amdgcn_global_load_lds(                                            \
      (const __attribute__((address_space(1))) unsigned int*)(gp),             \
      (__attribute__((address_space(3))) unsigned int*)(lp), 16, 0, 0)

// ---------------------------------------------------------------------------
// Kernel A: weight pre-pass. Wt[n][k] bf16, n in [0,1280):
//   n<1024: {wq,wk,wv,wg}[k][n&255]; n>=1024: wo[k][n&255].
// ---------------------------------------------------------------------------
__global__ __launch_bounds__(256) void wcat_kernel(
    const float* __restrict__ wq, const float* __restrict__ wk,
    const float* __restrict__ wv, const float* __restrict__ wg,
    const float* __restrict__ wo, unsigned short* __restrict__ wt) {
  __shared__ float tile[64][65];
  const int n0 = blockIdx.x * 64;  // 0..1216
  const int k0 = blockIdx.y * 64;
  const int wi = n0 >> 8;
  const float* src = (wi == 0) ? wq : (wi == 1) ? wk : (wi == 2) ? wv
                   : (wi == 3) ? wg : wo;
  const int col0 = n0 & 255;
  const int tx = threadIdx.x & 63;
  const int ty = threadIdx.x >> 6;
#pragma unroll
  for (int i = 0; i < 16; ++i) {
    int kl = ty + i * 4;
    tile[kl][tx] = src[(size_t)(k0 + kl) * 256 + col0 + tx];
  }
  __syncthreads();
#pragma unroll
  for (int i = 0; i < 16; ++i) {
    int nl = ty + i * 4;
    wt[(size_t)(n0 + nl) * 256 + k0 + tx] = f2bf(tile[tx][nl]);
  }
}

// ---------------------------------------------------------------------------
// Kernel B: fused LayerNorm -> bf16 x_ln in m-order (m = r*S + s).
// ---------------------------------------------------------------------------
__global__ __launch_bounds__(256) void ln_kernel(
    const float* __restrict__ msa, const float* __restrict__ ln_g,
    const float* __restrict__ ln_b, unsigned short* __restrict__ xln) {
  const int p = blockIdx.x * 4 + (threadIdx.x >> 6);
  const int lane = threadIdx.x & 63;
  const float4 v = ((const float4*)(msa + (size_t)p * C_DIM))[lane];
  float s = v.x + v.y + v.z + v.w;
  float ss = v.x * v.x + v.y * v.y + v.z * v.z + v.w * v.w;
#pragma unroll
  for (int o = 1; o < 64; o <<= 1) {
    s += __shfl_xor(s, o);
    ss += __shfl_xor(ss, o);
  }
  const float mu = s * (1.0f / C_DIM);
  const float rstd = rsqrtf(ss * (1.0f / C_DIM) - mu * mu + 1e-5f);
  const float4 g = ((const float4*)ln_g)[lane];
  const float4 b = ((const float4*)ln_b)[lane];
  const int sq = p / R_DIM;          // s
  const int r = p - sq * R_DIM;      // r
  const size_t m = (size_t)r * S_DIM + sq;
  ushort4 o;
  o.x = f2bf((v.x - mu) * rstd * g.x + b.x);
  o.y = f2bf((v.y - mu) * rstd * g.y + b.y);
  o.z = f2bf((v.z - mu) * rstd * g.z + b.z);
  o.w = f2bf((v.w - mu) * rstd * g.w + b.w);
  *(ushort4*)(xln + m * C_DIM + lane * 4) = o;
}

// ---------------------------------------------------------------------------
// Kernel C: projection GEMM v4 = v0 two-barrier K-loop (proven fastest)
//   + chunked XCD swizzle (proven: fetch 198->~50 MB; drains become L2-hit)
//   + LDS-transposed epilogue: 8x ushort8 16B stores/thread instead of
//     64x 2B scalar stores (128B-contiguous per 8-lane group).
// LDS = 16KB staging + 34KB Epi = 50KB -> 3 blocks/CU; regs ~132 unified.
// ---------------------------------------------------------------------------
#define EPI_S 136  // ushort stride: 272B, 16B-aligned rows; qd rows 4 apart
                   // land on bank offsets {0,16} -> only 2-way (free, m136)

__global__ __launch_bounds__(256, 3) void proj_kernel(
    const unsigned short* __restrict__ xln, const unsigned short* __restrict__ wt,
    const float* __restrict__ bg, unsigned short* __restrict__ q_ws,
    unsigned short* __restrict__ k_ws, unsigned short* __restrict__ v_ws,
    unsigned short* __restrict__ g_ws) {
  __shared__ __align__(16) unsigned short As[8 * 512];   // 8 KB
  __shared__ __align__(16) unsigned short Bs[8 * 512];   // 8 KB
  __shared__ __align__(16) unsigned short Epi[128 * EPI_S];  // 34 KB

  // chunked XCD swizzle: XCD x = bid%8 gets contiguous orig range
  // [x*768,(x+1)*768); n fastest within, so co-resident blocks on one XCD
  // share A-panels (L2-hit). 6144 % 8 == 0 -> bijective.
  const int bid = blockIdx.x;
  const int orig = (bid & 7) * 768 + (bid >> 3);
  const int n0 = (orig & 7) << 7;
  const int m0 = (orig >> 3) << 7;

  const int tid = threadIdx.x;
  const int wave = tid >> 6, lane = tid & 63;
  const int qd = lane >> 4, lm = lane & 15;
  const int wm = (wave & 1) * 64, wn = (wave >> 1) * 64;

  const int ga0 = wave * 2, ga1 = wave * 2 + 1;
  const unsigned short* agp0 = xln + (size_t)(m0 + ga0 * 16 + lm) * 256 + qd * 8;
  const unsigned short* agp1 = xln + (size_t)(m0 + ga1 * 16 + lm) * 256 + qd * 8;
  const unsigned short* bgp0 = wt + (size_t)(n0 + ga0 * 16 + lm) * 256 + qd * 8;
  const unsigned short* bgp1 = wt + (size_t)(n0 + ga1 * 16 + lm) * 256 + qd * 8;
  unsigned short* lA0 = &As[ga0 * 512];
  unsigned short* lA1 = &As[ga1 * 512];
  unsigned short* lB0 = &Bs[ga0 * 512];
  unsigned short* lB1 = &Bs[ga1 * 512];

  floatx4 acc[4][4];
#pragma unroll
  for (int i = 0; i < 4; ++i)
#pragma unroll
    for (int j = 0; j < 4; ++j) acc[i][j] = (floatx4){0.f, 0.f, 0.f, 0.f};

  for (int k0 = 0; k0 < 256; k0 += 32) {
    GLD_LDS16(agp0 + k0, lA0);
    GLD_LDS16(agp1 + k0, lA1);
    GLD_LDS16(bgp0 + k0, lB0);
    GLD_LDS16(bgp1 + k0, lB1);
    __syncthreads();
    short8 af[4], bf[4];
#pragma unroll
    for (int t = 0; t < 4; ++t) {
      af[t] = *(const short8*)((const char*)As + (size_t)(wm / 16 + t) * 1024 + lane * 16);
      bf[t] = *(const short8*)((const char*)Bs + (size_t)(wn / 16 + t) * 1024 + lane * 16);
    }
#pragma unroll
    for (int tm = 0; tm < 4; ++tm)
#pragma unroll
      for (int tn = 0; tn < 4; ++tn)
        acc[tm][tn] =
            __builtin_amdgcn_mfma_f32_16x16x32_bf16(af[tm], bf[tn], acc[tm][tn], 0, 0, 0);
    __syncthreads();
  }

  // ---- epilogue: transform -> Epi (bf16) -> 16B coalesced stores ----
  const int wi = n0 >> 8;          // uniform per block
  const int cb = n0 & 255;         // output col base (0 or 128)
#pragma unroll
  for (int tm = 0; tm < 4; ++tm)
#pragma unroll
    for (int tn = 0; tn < 4; ++tn) {
      float bgv = 0.0f;
      if (wi == 3) bgv = bg[cb + wn + tn * 16 + lm];
#pragma unroll
      for (int rg = 0; rg < 4; ++rg) {
        const int lr = wm + tm * 16 + qd * 4 + rg;
        const int lc = wn + tn * 16 + lm;
        const float val = acc[tm][tn][rg];
        unsigned short o;
        if (wi == 0) o = f2bf(val * 0.17677669529663689f);  // 1/sqrt(32)
        else if (wi == 3) o = f2bf(1.0f / (1.0f + __expf(-(val + bgv))));
        else o = f2bf(val);
        Epi[lr * EPI_S + lc] = o;
      }
    }
  __syncthreads();
  unsigned short* dst = (wi == 0) ? q_ws : (wi == 1) ? k_ws
                      : (wi == 2) ? v_ws : g_ws;
#pragma unroll
  for (int p = 0; p < 8; ++p) {
    const int lr = (p >> 1) * 32 + (tid >> 3);   // 0..127
    const int lc = (p & 1) * 64 + (tid & 7) * 8; // 0..120
    short8 v8 = *(const short8*)&Epi[lr * EPI_S + lc];
    *(short8*)(dst + (size_t)(m0 + lr) * 256 + cb + lc) = v8;
  }
}

// ---------------------------------------------------------------------------
// Kernel D: flash-style MFMA attention per (r, h) — unchanged.
// ---------------------------------------------------------------------------
#define PSTRIDE 40
#define VSTRIDE 264

__global__ __launch_bounds__(256) void attn_kernel(
    const unsigned short* __restrict__ q_ws, const unsigned short* __restrict__ k_ws,
    const unsigned short* __restrict__ v_ws, const unsigned short* __restrict__ g_ws,
    const float* __restrict__ mask, unsigned short* __restrict__ ctx_ws) {
  __shared__ __align__(16) unsigned short V_lds[32 * VSTRIDE];
  __shared__ __align__(16) unsigned short P_lds[4 * 16 * PSTRIDE];
  __shared__ float Bias[S_DIM];

  const int r = blockIdx.x;
  const int h = blockIdx.y;
  const int tid = threadIdx.x;
  const int wave = tid >> 6, lane = tid & 63;
  const int qd = lane >> 4, lm = lane & 15;
  const int qw = wave * 64;

  const size_t rS = (size_t)r * S_DIM;
  const int hb = h * AC_DIM;

  {
    const int s = tid;
    const unsigned short* vp = v_ws + (rS + s) * HC_DIM + hb;
    const int pos = (s & ~31) + ((s & 15) * 2) + ((s >> 4) & 1);
    uint4 u0 = *(const uint4*)(vp);
    uint4 u1 = *(const uint4*)(vp + 8);
    uint4 u2 = *(const uint4*)(vp + 16);
    uint4 u3 = *(const uint4*)(vp + 24);
    const unsigned w[16] = {u0.x, u0.y, u0.z, u0.w, u1.x, u1.y, u1.z, u1.w,
                            u2.x, u2.y, u2.z, u2.w, u3.x, u3.y, u3.z, u3.w};
#pragma unroll
    for (int d2 = 0; d2 < 16; ++d2) {
      V_lds[(d2 * 2 + 0) * VSTRIDE + pos] = (unsigned short)(w[d2] & 0xFFFF);
      V_lds[(d2 * 2 + 1) * VSTRIDE + pos] = (unsigned short)(w[d2] >> 16);
    }
    Bias[s] = 1e9f * (mask[(size_t)s * R_DIM + r] - 1.0f);
  }

  short8 qf[4];
#pragma unroll
  for (int qi = 0; qi < 4; ++qi)
    qf[qi] = *(const short8*)(q_ws + (rS + qw + qi * 16 + lm) * HC_DIM + hb + qd * 8);

  float m_st[4][4], l_st[4][4];
  floatx4 oacc[4][2];
#pragma unroll
  for (int qi = 0; qi < 4; ++qi) {
#pragma unroll
    for (int rg = 0; rg < 4; ++rg) {
      m_st[qi][rg] = -1e30f;
      l_st[qi][rg] = 0.0f;
    }
    oacc[qi][0] = (floatx4){0.f, 0.f, 0.f, 0.f};
    oacc[qi][1] = (floatx4){0.f, 0.f, 0.f, 0.f};
  }

  __syncthreads();

  unsigned short* Pw = &P_lds[wave * 16 * PSTRIDE];
  const floatx4 zero4 = (floatx4){0.f, 0.f, 0.f, 0.f};

  for (int ch = 0; ch < 8; ++ch) {
    const int kb = ch * 32;
    const float b0 = Bias[kb + lm];
    const float b1 = Bias[kb + 16 + lm];
    short8 kf0 = *(const short8*)(k_ws + (rS + kb + lm) * HC_DIM + hb + qd * 8);
    short8 kf1 = *(const short8*)(k_ws + (rS + kb + 16 + lm) * HC_DIM + hb + qd * 8);
    short8 vf0 = *(const short8*)&V_lds[lm * VSTRIDE + kb + qd * 8];
    short8 vf1 = *(const short8*)&V_lds[(16 + lm) * VSTRIDE + kb + qd * 8];

#pragma unroll
    for (int qi = 0; qi < 4; ++qi) {
      floatx4 s0 = __builtin_amdgcn_mfma_f32_16x16x32_bf16(qf[qi], kf0, zero4, 0, 0, 0);
      floatx4 s1 = __builtin_amdgcn_mfma_f32_16x16x32_bf16(qf[qi], kf1, zero4, 0, 0, 0);
      unsigned pw[4];
#pragma unroll
      for (int rg = 0; rg < 4; ++rg) {
        float a0 = s0[rg] + b0;
        float a1 = s1[rg] + b1;
        float t = fmaxf(a0, a1);
        t = fmaxf(t, __shfl_xor(t, 1));
        t = fmaxf(t, __shfl_xor(t, 2));
        t = fmaxf(t, __shfl_xor(t, 4));
        t = fmaxf(t, __shfl_xor(t, 8));
        float mold = m_st[qi][rg];
        float mnew = fmaxf(mold, t);
        float alpha = __expf(mold - mnew);
        float p0 = __expf(a0 - mnew);
        float p1 = __expf(a1 - mnew);
        float rs = p0 + p1;
        rs += __shfl_xor(rs, 1);
        rs += __shfl_xor(rs, 2);
        rs += __shfl_xor(rs, 4);
        rs += __shfl_xor(rs, 8);
        l_st[qi][rg] = l_st[qi][rg] * alpha + rs;
        m_st[qi][rg] = mnew;
        oacc[qi][0][rg] *= alpha;
        oacc[qi][1][rg] *= alpha;
        pw[rg] = packbf2(p0, p1);
      }
      unsigned* pbase = (unsigned*)Pw;
#pragma unroll
      for (int rg = 0; rg < 4; ++rg)
        pbase[((qd * 4 + rg) * PSTRIDE) / 2 + lm] = pw[rg];
      short8 pa = *(const short8*)&Pw[lm * PSTRIDE + qd * 8];
      oacc[qi][0] = __builtin_amdgcn_mfma_f32_16x16x32_bf16(pa, vf0, oacc[qi][0], 0, 0, 0);
      oacc[qi][1] = __builtin_amdgcn_mfma_f32_16x16x32_bf16(pa, vf1, oacc[qi][1], 0, 0, 0);
    }
  }

#pragma unroll
  for (int qi = 0; qi < 4; ++qi) {
#pragma unroll
    for (int rg = 0; rg < 4; ++rg) {
      const float inv = 1.0f / l_st[qi][rg];
      const int row = qw + qi * 16 + qd * 4 + rg;
      const size_t base = (rS + row) * HC_DIM + hb;
      float o0 = oacc[qi][0][rg] * inv * bf2f(g_ws[base + lm]);
      float o1 = oacc[qi][1][rg] * inv * bf2f(g_ws[base + 16 + lm]);
      ctx_ws[base + lm] = f2bf(o0);
      ctx_ws[base + 16 + lm] = f2bf(o1);
    }
  }
}

// ---------------------------------------------------------------------------
// Kernel E: out = ctx @ wo + bo -> fp32 [S,R,C]. v0 K-loop + XCD swizzle
// + LDS-transposed epilogue (fp32, two 64-row halves -> 16B float4 stores,
// 512B contiguous per output row).
// ---------------------------------------------------------------------------
#define EPF_S 132  // float stride: 528B rows, 16B-aligned

__global__ __launch_bounds__(256, 3) void out_kernel(
    const unsigned short* __restrict__ ctx, const unsigned short* __restrict__ wot,
    const float* __restrict__ bo, float* __restrict__ out) {
  __shared__ __align__(16) unsigned short As[8 * 512];  // 8 KB
  __shared__ __align__(16) unsigned short Bs[8 * 512];  // 8 KB
  __shared__ __align__(16) float Epif[64 * EPF_S];      // 33 KB

  const int bid = blockIdx.x;  // 1536; 1536 % 8 == 0 -> bijective
  const int orig = (bid & 7) * 192 + (bid >> 3);
  const int n0 = (orig & 1) << 7;
  const int m0 = (orig >> 1) << 7;

  const int tid = threadIdx.x;
  const int wave = tid >> 6, lane = tid & 63;
  const int qd = lane >> 4, lm = lane & 15;
  const int wm = (wave & 1) * 64, wn = (wave >> 1) * 64;

  const int ga0 = wave * 2, ga1 = wave * 2 + 1;
  const unsigned short* agp0 = ctx + (size_t)(m0 + ga0 * 16 + lm) * 256 + qd * 8;
  const unsigned short* agp1 = ctx + (size_t)(m0 + ga1 * 16 + lm) * 256 + qd * 8;
  const unsigned short* bgp0 = wot + (size_t)(n0 + ga0 * 16 + lm) * 256 + qd * 8;
  const unsigned short* bgp1 = wot + (size_t)(n0 + ga1 * 16 + lm) * 256 + qd * 8;
  unsigned short* lA0 = &As[ga0 * 512];
  unsigned short* lA1 = &As[ga1 * 512];
  unsigned short* lB0 = &Bs[ga0 * 512];
  unsigned short* lB1 = &Bs[ga1 * 512];

  floatx4 acc[4][4];
#pragma unroll
  for (int i = 0; i < 4; ++i)
#pragma unroll
    for (int j = 0; j < 4; ++j) acc[i][j] = (floatx4){0.f, 0.f, 0.f, 0.f};

  for (int k0 = 0; k0 < 256; k0 += 32) {
    GLD_LDS16(agp0 + k0, lA0);
    GLD_LDS16(agp1 + k0, lA1);
    GLD_LDS16(bgp0 + k0, lB0);
    GLD_LDS16(bgp1 + k0, lB1);
    __syncthreads();
    short8 af[4], bf[4];
#pragma unroll
    for (int t = 0; t < 4; ++t) {
      af[t] = *(const short8*)((const char*)As + (size_t)(wm / 16 + t) * 1024 + lane * 16);
      bf[t] = *(const short8*)((const char*)Bs + (size_t)(wn / 16 + t) * 1024 + lane * 16);
    }
#pragma unroll
    for (int tm = 0; tm < 4; ++tm)
#pragma unroll
      for (int tn = 0; tn < 4; ++tn)
        acc[tm][tn] =
            __builtin_amdgcn_mfma_f32_16x16x32_bf16(af[tm], bf[tn], acc[tm][tn], 0, 0, 0);
    __syncthreads();
  }

  // ---- epilogue: two 64-row halves through Epif, float4 stores ----
#pragma unroll
  for (int h = 0; h < 2; ++h) {
    __syncthreads();
    if (wm == h * 64) {  // waves h and h+2 own these rows
#pragma unroll
      for (int tm = 0; tm < 4; ++tm)
#pragma unroll
        for (int tn = 0; tn < 4; ++tn) {
          const float bov = bo[n0 + wn + tn * 16 + lm];
#pragma unroll
          for (int rg = 0; rg < 4; ++rg) {
            const int lr = tm * 16 + qd * 4 + rg;   // 0..63 local
            const int lc = wn + tn * 16 + lm;
            Epif[lr * EPF_S + lc] = acc[tm][tn][rg] + bov;
          }
        }
    }
    __syncthreads();
#pragma unroll
    for (int p = 0; p < 8; ++p) {
      const int lr = p * 8 + (tid >> 5);     // 0..63
      const int lc = (tid & 31) * 4;         // 0..124
      float4 vv = *(const float4*)&Epif[lr * EPF_S + lc];
      const int m = m0 + h * 64 + lr;
      const int rr = m >> 8, sc = m & 255;
      *(float4*)(out + ((size_t)sc * R_DIM + rr) * C_DIM + n0 + lc) = vv;
    }
  }
}

// ---------------------------------------------------------------------------
extern "C" void kernel_launch(void* const* d_in, const int* in_sizes, int n_in,
                              void* d_out, int out_size, void* d_ws, size_t ws_size,
                              hipStream_t stream) {
  const float* msa = (const float*)d_in[0];
  const float* mask = (const float*)d_in[1];
  const float* ln_g = (const float*)d_in[2];
  const float* ln_b = (const float*)d_in[3];
  const float* wq = (const float*)d_in[4];
  const float* wk = (const float*)d_in[5];
  const float* wv = (const float*)d_in[6];
  const float* wg = (const float*)d_in[7];
  const float* bg = (const float*)d_in[8];
  const float* wo = (const float*)d_in[9];
  const float* bo = (const float*)d_in[10];
  float* out = (float*)d_out;

  // workspace carve (~252.3 MB): Wt | x_ln (aliased as ctx) | q | k | v | g
  unsigned short* wt = (unsigned short*)d_ws;
  unsigned short* xln = wt + (size_t)1280 * 256;
  unsigned short* q_ws = xln + (size_t)M_DIM * 256;
  unsigned short* k_ws = q_ws + (size_t)M_DIM * 256;
  unsigned short* v_ws = k_ws + (size_t)M_DIM * 256;
  unsigned short* g_ws = v_ws + (size_t)M_DIM * 256;
  unsigned short* ctx_ws = xln;  // alias: x_ln dead after proj
  unsigned short* wot = wt + (size_t)1024 * 256;

  hipLaunchKernelGGL(wcat_kernel, dim3(20, 4), dim3(256), 0, stream,
                     wq, wk, wv, wg, wo, wt);
  hipLaunchKernelGGL(ln_kernel, dim3(M_DIM / 4), dim3(256), 0, stream,
                     msa, ln_g, ln_b, xln);
  hipLaunchKernelGGL(proj_kernel, dim3(6144), dim3(256), 0, stream,
                     xln, wt, bg, q_ws, k_ws, v_ws, g_ws);
  hipLaunchKernelGGL(attn_kernel, dim3(R_DIM, H_DIM), dim3(256), 0, stream,
                     q_ws, k_ws, v_ws, g_ws, mask, ctx_ws);
  hipLaunchKernelGGL(out_kernel, dim3(1536), dim3(256), 0, stream,
                     ctx_ws, wot, bo, out);
}

// Round 5
// 460.208 us; speedup vs baseline: 1.8091x; 1.1990x over previous
//
#include <hip/hip_runtime.h>

#define S_DIM 256
#define R_DIM 384
#define C_DIM 256
#define H_DIM 8
#define AC_DIM 32
#define HC_DIM 256
#define M_DIM (S_DIM * R_DIM)  // 98304 rows, m = r*S + s

typedef __attribute__((ext_vector_type(8))) short short8;
typedef __attribute__((ext_vector_type(4))) float floatx4;
typedef __attribute__((ext_vector_type(2))) unsigned int uint2v;

__device__ __forceinline__ unsigned short f2bf(float f) {
  unsigned u = __float_as_uint(f);
  u += 0x7FFFu + ((u >> 16) & 1u);  // round-to-nearest-even
  return (unsigned short)(u >> 16);
}
__device__ __forceinline__ float bf2f(unsigned short s) {
  return __uint_as_float(((unsigned)s) << 16);
}
__device__ __forceinline__ unsigned packbf2(float a, float b) {
  return (unsigned)f2bf(a) | ((unsigned)f2bf(b) << 16);
}

// async global->LDS, 16B per lane; LDS dest = wave-uniform base + lane*16
#define GLD_LDS16(gp, lp)                                                      \
  __builtin_amdgcn_global_load_lds(                                            \
      (const __attribute__((address_space(1))) unsigned int*)(gp),             \
      (__attribute__((address_space(3))) unsigned int*)(lp), 16, 0, 0)

// ---------------------------------------------------------------------------
// Kernel A: weight pre-pass. Wt[n][k] bf16, n in [0,1280):
//   n<1024: {wq,wk,wv,wg}[k][n&255]; n>=1024: wo[k][n&255].
// ---------------------------------------------------------------------------
__global__ __launch_bounds__(256) void wcat_kernel(
    const float* __restrict__ wq, const float* __restrict__ wk,
    const float* __restrict__ wv, const float* __restrict__ wg,
    const float* __restrict__ wo, unsigned short* __restrict__ wt) {
  __shared__ float tile[64][65];
  const int n0 = blockIdx.x * 64;  // 0..1216
  const int k0 = blockIdx.y * 64;
  const int wi = n0 >> 8;
  const float* src = (wi == 0) ? wq : (wi == 1) ? wk : (wi == 2) ? wv
                   : (wi == 3) ? wg : wo;
  const int col0 = n0 & 255;
  const int tx = threadIdx.x & 63;
  const int ty = threadIdx.x >> 6;
#pragma unroll
  for (int i = 0; i < 16; ++i) {
    int kl = ty + i * 4;
    tile[kl][tx] = src[(size_t)(k0 + kl) * 256 + col0 + tx];
  }
  __syncthreads();
#pragma unroll
  for (int i = 0; i < 16; ++i) {
    int nl = ty + i * 4;
    wt[(size_t)(n0 + nl) * 256 + k0 + tx] = f2bf(tile[tx][nl]);
  }
}

// ---------------------------------------------------------------------------
// Kernel B: fused LayerNorm -> bf16 x_ln in m-order (m = r*S + s).
// ---------------------------------------------------------------------------
__global__ __launch_bounds__(256) void ln_kernel(
    const float* __restrict__ msa, const float* __restrict__ ln_g,
    const float* __restrict__ ln_b, unsigned short* __restrict__ xln) {
  const int p = blockIdx.x * 4 + (threadIdx.x >> 6);
  const int lane = threadIdx.x & 63;
  const float4 v = ((const float4*)(msa + (size_t)p * C_DIM))[lane];
  float s = v.x + v.y + v.z + v.w;
  float ss = v.x * v.x + v.y * v.y + v.z * v.z + v.w * v.w;
#pragma unroll
  for (int o = 1; o < 64; o <<= 1) {
    s += __shfl_xor(s, o);
    ss += __shfl_xor(ss, o);
  }
  const float mu = s * (1.0f / C_DIM);
  const float rstd = rsqrtf(ss * (1.0f / C_DIM) - mu * mu + 1e-5f);
  const float4 g = ((const float4*)ln_g)[lane];
  const float4 b = ((const float4*)ln_b)[lane];
  const int sq = p / R_DIM;          // s
  const int r = p - sq * R_DIM;      // r
  const size_t m = (size_t)r * S_DIM + sq;
  ushort4 o;
  o.x = f2bf((v.x - mu) * rstd * g.x + b.x);
  o.y = f2bf((v.y - mu) * rstd * g.y + b.y);
  o.z = f2bf((v.z - mu) * rstd * g.z + b.z);
  o.w = f2bf((v.w - mu) * rstd * g.w + b.w);
  *(ushort4*)(xln + m * C_DIM + lane * 4) = o;
}

// ---------------------------------------------------------------------------
// Kernel C: projection GEMM v4 (unchanged from round 4, passing 551.8us).
// ---------------------------------------------------------------------------
#define EPI_S 136

__global__ __launch_bounds__(256, 3) void proj_kernel(
    const unsigned short* __restrict__ xln, const unsigned short* __restrict__ wt,
    const float* __restrict__ bg, unsigned short* __restrict__ q_ws,
    unsigned short* __restrict__ k_ws, unsigned short* __restrict__ v_ws,
    unsigned short* __restrict__ g_ws) {
  __shared__ __align__(16) unsigned short As[8 * 512];   // 8 KB
  __shared__ __align__(16) unsigned short Bs[8 * 512];   // 8 KB
  __shared__ __align__(16) unsigned short Epi[128 * EPI_S];  // 34 KB

  const int bid = blockIdx.x;
  const int orig = (bid & 7) * 768 + (bid >> 3);
  const int n0 = (orig & 7) << 7;
  const int m0 = (orig >> 3) << 7;

  const int tid = threadIdx.x;
  const int wave = tid >> 6, lane = tid & 63;
  const int qd = lane >> 4, lm = lane & 15;
  const int wm = (wave & 1) * 64, wn = (wave >> 1) * 64;

  const int ga0 = wave * 2, ga1 = wave * 2 + 1;
  const unsigned short* agp0 = xln + (size_t)(m0 + ga0 * 16 + lm) * 256 + qd * 8;
  const unsigned short* agp1 = xln + (size_t)(m0 + ga1 * 16 + lm) * 256 + qd * 8;
  const unsigned short* bgp0 = wt + (size_t)(n0 + ga0 * 16 + lm) * 256 + qd * 8;
  const unsigned short* bgp1 = wt + (size_t)(n0 + ga1 * 16 + lm) * 256 + qd * 8;
  unsigned short* lA0 = &As[ga0 * 512];
  unsigned short* lA1 = &As[ga1 * 512];
  unsigned short* lB0 = &Bs[ga0 * 512];
  unsigned short* lB1 = &Bs[ga1 * 512];

  floatx4 acc[4][4];
#pragma unroll
  for (int i = 0; i < 4; ++i)
#pragma unroll
    for (int j = 0; j < 4; ++j) acc[i][j] = (floatx4){0.f, 0.f, 0.f, 0.f};

  for (int k0 = 0; k0 < 256; k0 += 32) {
    GLD_LDS16(agp0 + k0, lA0);
    GLD_LDS16(agp1 + k0, lA1);
    GLD_LDS16(bgp0 + k0, lB0);
    GLD_LDS16(bgp1 + k0, lB1);
    __syncthreads();
    short8 af[4], bf[4];
#pragma unroll
    for (int t = 0; t < 4; ++t) {
      af[t] = *(const short8*)((const char*)As + (size_t)(wm / 16 + t) * 1024 + lane * 16);
      bf[t] = *(const short8*)((const char*)Bs + (size_t)(wn / 16 + t) * 1024 + lane * 16);
    }
#pragma unroll
    for (int tm = 0; tm < 4; ++tm)
#pragma unroll
      for (int tn = 0; tn < 4; ++tn)
        acc[tm][tn] =
            __builtin_amdgcn_mfma_f32_16x16x32_bf16(af[tm], bf[tn], acc[tm][tn], 0, 0, 0);
    __syncthreads();
  }

  const int wi = n0 >> 8;
  const int cb = n0 & 255;
#pragma unroll
  for (int tm = 0; tm < 4; ++tm)
#pragma unroll
    for (int tn = 0; tn < 4; ++tn) {
      float bgv = 0.0f;
      if (wi == 3) bgv = bg[cb + wn + tn * 16 + lm];
#pragma unroll
      for (int rg = 0; rg < 4; ++rg) {
        const int lr = wm + tm * 16 + qd * 4 + rg;
        const int lc = wn + tn * 16 + lm;
        const float val = acc[tm][tn][rg];
        unsigned short o;
        if (wi == 0) o = f2bf(val * 0.17677669529663689f);  // 1/sqrt(32)
        else if (wi == 3) o = f2bf(1.0f / (1.0f + __expf(-(val + bgv))));
        else o = f2bf(val);
        Epi[lr * EPI_S + lc] = o;
      }
    }
  __syncthreads();
  unsigned short* dst = (wi == 0) ? q_ws : (wi == 1) ? k_ws
                      : (wi == 2) ? v_ws : g_ws;
#pragma unroll
  for (int p = 0; p < 8; ++p) {
    const int lr = (p >> 1) * 32 + (tid >> 3);   // 0..127
    const int lc = (p & 1) * 64 + (tid & 7) * 8; // 0..120
    short8 v8 = *(const short8*)&Epi[lr * EPI_S + lc];
    *(short8*)(dst + (size_t)(m0 + lr) * 256 + cb + lc) = v8;
  }
}

// ---------------------------------------------------------------------------
// Kernel D: flash attention v2 — swapped QK^T (score[k][q] layout) so the
// row-softmax reduces IN-REGISTER over 8 k-values + 2 shuffles over
// qd-groups (vs 32 shuffles before). m/l state per q-col (uniform over qd).
// Defer-max (T13, THR=8): rescale path (incl. alpha broadcast) taken only
// when the tile max actually grows. P stored in natural k-order, so the
// V staging scramble becomes identity (pos=s). PV fragments unchanged.
// ---------------------------------------------------------------------------
#define PSTRIDE 40
#define VSTRIDE 264

__global__ __launch_bounds__(256) void attn_kernel(
    const unsigned short* __restrict__ q_ws, const unsigned short* __restrict__ k_ws,
    const unsigned short* __restrict__ v_ws, const unsigned short* __restrict__ g_ws,
    const float* __restrict__ mask, unsigned short* __restrict__ ctx_ws) {
  __shared__ __align__(16) unsigned short V_lds[32 * VSTRIDE];
  __shared__ __align__(16) unsigned short P_lds[4 * 16 * PSTRIDE];
  __shared__ float Bias[S_DIM];

  const int r = blockIdx.x;
  const int h = blockIdx.y;
  const int tid = threadIdx.x;
  const int wave = tid >> 6, lane = tid & 63;
  const int qd = lane >> 4, lm = lane & 15;
  const int qw = wave * 64;

  const size_t rS = (size_t)r * S_DIM;
  const int hb = h * AC_DIM;

  {
    const int s = tid;
    const unsigned short* vp = v_ws + (rS + s) * HC_DIM + hb;
    uint4 u0 = *(const uint4*)(vp);
    uint4 u1 = *(const uint4*)(vp + 8);
    uint4 u2 = *(const uint4*)(vp + 16);
    uint4 u3 = *(const uint4*)(vp + 24);
    const unsigned w[16] = {u0.x, u0.y, u0.z, u0.w, u1.x, u1.y, u1.z, u1.w,
                            u2.x, u2.y, u2.z, u2.w, u3.x, u3.y, u3.z, u3.w};
#pragma unroll
    for (int d2 = 0; d2 < 16; ++d2) {
      V_lds[(d2 * 2 + 0) * VSTRIDE + s] = (unsigned short)(w[d2] & 0xFFFF);
      V_lds[(d2 * 2 + 1) * VSTRIDE + s] = (unsigned short)(w[d2] >> 16);
    }
    Bias[s] = 1e9f * (mask[(size_t)s * R_DIM + r] - 1.0f);
  }

  short8 qf[4];
#pragma unroll
  for (int qi = 0; qi < 4; ++qi)
    qf[qi] = *(const short8*)(q_ws + (rS + qw + qi * 16 + lm) * HC_DIM + hb + qd * 8);

  float m_q[4], l_q[4];        // per q-col = lm (uniform across qd)
  floatx4 oacc[4][2];
#pragma unroll
  for (int qi = 0; qi < 4; ++qi) {
    m_q[qi] = -1e30f;
    l_q[qi] = 0.0f;
    oacc[qi][0] = (floatx4){0.f, 0.f, 0.f, 0.f};
    oacc[qi][1] = (floatx4){0.f, 0.f, 0.f, 0.f};
  }

  __syncthreads();

  unsigned short* Pw = &P_lds[wave * 16 * PSTRIDE];
  const floatx4 zero4 = (floatx4){0.f, 0.f, 0.f, 0.f};
  const int qd4 = qd * 4;

  for (int ch = 0; ch < 8; ++ch) {
    const int kb = ch * 32;
    short8 kf0 = *(const short8*)(k_ws + (rS + kb + lm) * HC_DIM + hb + qd * 8);
    short8 kf1 = *(const short8*)(k_ws + (rS + kb + 16 + lm) * HC_DIM + hb + qd * 8);
    short8 vf0 = *(const short8*)&V_lds[lm * VSTRIDE + kb + qd * 8];
    short8 vf1 = *(const short8*)&V_lds[(16 + lm) * VSTRIDE + kb + qd * 8];
    const floatx4 bl = *(const floatx4*)&Bias[kb + qd4];
    const floatx4 bh = *(const floatx4*)&Bias[kb + 16 + qd4];

#pragma unroll
    for (int qi = 0; qi < 4; ++qi) {
      // swapped: s[rg] = score[k = kb(+16) + qd*4+rg][q = lm]
      floatx4 s0 = __builtin_amdgcn_mfma_f32_16x16x32_bf16(kf0, qf[qi], zero4, 0, 0, 0);
      floatx4 s1 = __builtin_amdgcn_mfma_f32_16x16x32_bf16(kf1, qf[qi], zero4, 0, 0, 0);
      s0 += bl;
      s1 += bh;
      // tile max over k: 7 in-reg fmax + 2 shuffles over qd-groups
      float t = fmaxf(fmaxf(fmaxf(s0[0], s0[1]), fmaxf(s0[2], s0[3])),
                      fmaxf(fmaxf(s1[0], s1[1]), fmaxf(s1[2], s1[3])));
      t = fmaxf(t, __shfl_xor(t, 16));
      t = fmaxf(t, __shfl_xor(t, 32));
      float mold = m_q[qi];
      if (__any(t > mold + 8.0f)) {  // defer-max: rare after ch 0
        const float mnew = fmaxf(mold, t);
        const float alpha = __expf(mold - mnew);
#pragma unroll
        for (int rg = 0; rg < 4; ++rg) {
          const float arg = __shfl(alpha, qd4 + rg);  // alpha for q-row qd*4+rg
          oacc[qi][0][rg] *= arg;
          oacc[qi][1][rg] *= arg;
        }
        l_q[qi] *= alpha;
        m_q[qi] = mnew;
        mold = mnew;
      }
      floatx4 p0, p1;
#pragma unroll
      for (int rg = 0; rg < 4; ++rg) {
        p0[rg] = __expf(s0[rg] - mold);
        p1[rg] = __expf(s1[rg] - mold);
      }
      float rs = ((p0[0] + p0[1]) + (p0[2] + p0[3])) +
                 ((p1[0] + p1[1]) + (p1[2] + p1[3]));
      rs += __shfl_xor(rs, 16);
      rs += __shfl_xor(rs, 32);
      l_q[qi] += rs;
      // P -> LDS, natural k-order: row = q-col lm; lo k=qd*4.., hi k=16+qd*4..
      unsigned* prow = (unsigned*)&Pw[lm * PSTRIDE];
      uint2v lo = {packbf2(p0[0], p0[1]), packbf2(p0[2], p0[3])};
      uint2v hi = {packbf2(p1[0], p1[1]), packbf2(p1[2], p1[3])};
      *(uint2v*)&prow[qd * 2] = lo;
      *(uint2v*)&prow[8 + qd * 2] = hi;
      short8 pa = *(const short8*)&Pw[lm * PSTRIDE + qd * 8];
      oacc[qi][0] = __builtin_amdgcn_mfma_f32_16x16x32_bf16(pa, vf0, oacc[qi][0], 0, 0, 0);
      oacc[qi][1] = __builtin_amdgcn_mfma_f32_16x16x32_bf16(pa, vf1, oacc[qi][1], 0, 0, 0);
    }
  }

#pragma unroll
  for (int qi = 0; qi < 4; ++qi) {
    const float lq = l_q[qi];
#pragma unroll
    for (int rg = 0; rg < 4; ++rg) {
      const float inv = 1.0f / __shfl(lq, qd4 + rg);  // l for q-row qd*4+rg
      const int row = qw + qi * 16 + qd4 + rg;
      const size_t base = (rS + row) * HC_DIM + hb;
      float o0 = oacc[qi][0][rg] * inv * bf2f(g_ws[base + lm]);
      float o1 = oacc[qi][1][rg] * inv * bf2f(g_ws[base + 16 + lm]);
      ctx_ws[base + lm] = f2bf(o0);
      ctx_ws[base + 16 + lm] = f2bf(o1);
    }
  }
}

// ---------------------------------------------------------------------------
// Kernel E: out = ctx @ wo + bo -> fp32 [S,R,C] (unchanged from round 4).
// ---------------------------------------------------------------------------
#define EPF_S 132

__global__ __launch_bounds__(256, 3) void out_kernel(
    const unsigned short* __restrict__ ctx, const unsigned short* __restrict__ wot,
    const float* __restrict__ bo, float* __restrict__ out) {
  __shared__ __align__(16) unsigned short As[8 * 512];  // 8 KB
  __shared__ __align__(16) unsigned short Bs[8 * 512];  // 8 KB
  __shared__ __align__(16) float Epif[64 * EPF_S];      // 33 KB

  const int bid = blockIdx.x;  // 1536; 1536 % 8 == 0 -> bijective
  const int orig = (bid & 7) * 192 + (bid >> 3);
  const int n0 = (orig & 1) << 7;
  const int m0 = (orig >> 1) << 7;

  const int tid = threadIdx.x;
  const int wave = tid >> 6, lane = tid & 63;
  const int qd = lane >> 4, lm = lane & 15;
  const int wm = (wave & 1) * 64, wn = (wave >> 1) * 64;

  const int ga0 = wave * 2, ga1 = wave * 2 + 1;
  const unsigned short* agp0 = ctx + (size_t)(m0 + ga0 * 16 + lm) * 256 + qd * 8;
  const unsigned short* agp1 = ctx + (size_t)(m0 + ga1 * 16 + lm) * 256 + qd * 8;
  const unsigned short* bgp0 = wot + (size_t)(n0 + ga0 * 16 + lm) * 256 + qd * 8;
  const unsigned short* bgp1 = wot + (size_t)(n0 + ga1 * 16 + lm) * 256 + qd * 8;
  unsigned short* lA0 = &As[ga0 * 512];
  unsigned short* lA1 = &As[ga1 * 512];
  unsigned short* lB0 = &Bs[ga0 * 512];
  unsigned short* lB1 = &Bs[ga1 * 512];

  floatx4 acc[4][4];
#pragma unroll
  for (int i = 0; i < 4; ++i)
#pragma unroll
    for (int j = 0; j < 4; ++j) acc[i][j] = (floatx4){0.f, 0.f, 0.f, 0.f};

  for (int k0 = 0; k0 < 256; k0 += 32) {
    GLD_LDS16(agp0 + k0, lA0);
    GLD_LDS16(agp1 + k0, lA1);
    GLD_LDS16(bgp0 + k0, lB0);
    GLD_LDS16(bgp1 + k0, lB1);
    __syncthreads();
    short8 af[4], bf[4];
#pragma unroll
    for (int t = 0; t < 4; ++t) {
      af[t] = *(const short8*)((const char*)As + (size_t)(wm / 16 + t) * 1024 + lane * 16);
      bf[t] = *(const short8*)((const char*)Bs + (size_t)(wn / 16 + t) * 1024 + lane * 16);
    }
#pragma unroll
    for (int tm = 0; tm < 4; ++tm)
#pragma unroll
      for (int tn = 0; tn < 4; ++tn)
        acc[tm][tn] =
            __builtin_amdgcn_mfma_f32_16x16x32_bf16(af[tm], bf[tn], acc[tm][tn], 0, 0, 0);
    __syncthreads();
  }

#pragma unroll
  for (int h = 0; h < 2; ++h) {
    __syncthreads();
    if (wm == h * 64) {
#pragma unroll
      for (int tm = 0; tm < 4; ++tm)
#pragma unroll
        for (int tn = 0; tn < 4; ++tn) {
          const float bov = bo[n0 + wn + tn * 16 + lm];
#pragma unroll
          for (int rg = 0; rg < 4; ++rg) {
            const int lr = tm * 16 + qd * 4 + rg;   // 0..63 local
            const int lc = wn + tn * 16 + lm;
            Epif[lr * EPF_S + lc] = acc[tm][tn][rg] + bov;
          }
        }
    }
    __syncthreads();
#pragma unroll
    for (int p = 0; p < 8; ++p) {
      const int lr = p * 8 + (tid >> 5);     // 0..63
      const int lc = (tid & 31) * 4;         // 0..124
      float4 vv = *(const float4*)&Epif[lr * EPF_S + lc];
      const int m = m0 + h * 64 + lr;
      const int rr = m >> 8, sc = m & 255;
      *(float4*)(out + ((size_t)sc * R_DIM + rr) * C_DIM + n0 + lc) = vv;
    }
  }
}

// ---------------------------------------------------------------------------
extern "C" void kernel_launch(void* const* d_in, const int* in_sizes, int n_in,
                              void* d_out, int out_size, void* d_ws, size_t ws_size,
                              hipStream_t stream) {
  const float* msa = (const float*)d_in[0];
  const float* mask = (const float*)d_in[1];
  const float* ln_g = (const float*)d_in[2];
  const float* ln_b = (const float*)d_in[3];
  const float* wq = (const float*)d_in[4];
  const float* wk = (const float*)d_in[5];
  const float* wv = (const float*)d_in[6];
  const float* wg = (const float*)d_in[7];
  const float* bg = (const float*)d_in[8];
  const float* wo = (const float*)d_in[9];
  const float* bo = (const float*)d_in[10];
  float* out = (float*)d_out;

  // workspace carve (~252.3 MB): Wt | x_ln (aliased as ctx) | q | k | v | g
  unsigned short* wt = (unsigned short*)d_ws;
  unsigned short* xln = wt + (size_t)1280 * 256;
  unsigned short* q_ws = xln + (size_t)M_DIM * 256;
  unsigned short* k_ws = q_ws + (size_t)M_DIM * 256;
  unsigned short* v_ws = k_ws + (size_t)M_DIM * 256;
  unsigned short* g_ws = v_ws + (size_t)M_DIM * 256;
  unsigned short* ctx_ws = xln;  // alias: x_ln dead after proj
  unsigned short* wot = wt + (size_t)1024 * 256;

  hipLaunchKernelGGL(wcat_kernel, dim3(20, 4), dim3(256), 0, stream,
                     wq, wk, wv, wg, wo, wt);
  hipLaunchKernelGGL(ln_kernel, dim3(M_DIM / 4), dim3(256), 0, stream,
                     msa, ln_g, ln_b, xln);
  hipLaunchKernelGGL(proj_kernel, dim3(6144), dim3(256), 0, stream,
                     xln, wt, bg, q_ws, k_ws, v_ws, g_ws);
  hipLaunchKernelGGL(attn_kernel, dim3(R_DIM, H_DIM), dim3(256), 0, stream,
                     q_ws, k_ws, v_ws, g_ws, mask, ctx_ws);
  hipLaunchKernelGGL(out_kernel, dim3(1536), dim3(256), 0, stream,
                     ctx_ws, wot, bo, out);
}